// Round 1
// baseline (1402.835 us; speedup 1.0000x reference)
//
#include <hip/hip_runtime.h>

#define D 128
#define D4 32   // floats4 per row

// ---------- CSR build ----------
__global__ __launch_bounds__(256) void k_hist(const int* __restrict__ dst, int* __restrict__ deg, int E) {
    int e = blockIdx.x * 256 + threadIdx.x;
    if (e < E) atomicAdd(&deg[dst[e]], 1);
}

__global__ __launch_bounds__(1024) void k_scan1(const int* __restrict__ deg, int* __restrict__ rowstart,
                                                int* __restrict__ bsum, int N) {
    __shared__ int sd[1024];
    int i = blockIdx.x * 1024 + threadIdx.x;
    int v = (i < N) ? deg[i] : 0;
    sd[threadIdx.x] = v; __syncthreads();
    for (int off = 1; off < 1024; off <<= 1) {
        int t = (threadIdx.x >= off) ? sd[threadIdx.x - off] : 0;
        __syncthreads();
        sd[threadIdx.x] += t;
        __syncthreads();
    }
    if (i < N) rowstart[i] = sd[threadIdx.x] - v;   // exclusive
    if (threadIdx.x == 1023) bsum[blockIdx.x] = sd[1023];
}

__global__ __launch_bounds__(1024) void k_scan2(const int* __restrict__ bsum, int* __restrict__ bofs, int M) {
    __shared__ int sd[1024];
    int v = (threadIdx.x < M) ? bsum[threadIdx.x] : 0;
    sd[threadIdx.x] = v; __syncthreads();
    for (int off = 1; off < 1024; off <<= 1) {
        int t = (threadIdx.x >= off) ? sd[threadIdx.x - off] : 0;
        __syncthreads();
        sd[threadIdx.x] += t;
        __syncthreads();
    }
    if (threadIdx.x < M) bofs[threadIdx.x] = sd[threadIdx.x] - v;  // exclusive
}

__global__ __launch_bounds__(1024) void k_scan3(int* rowstart, const int* __restrict__ bofs, int N) {
    int i = blockIdx.x * 1024 + threadIdx.x;
    if (i < N) rowstart[i] += bofs[blockIdx.x];
}

__global__ __launch_bounds__(256) void k_fill(const int* __restrict__ src, const int* __restrict__ dst,
                                              const int* __restrict__ rowstart, int* __restrict__ cursor,
                                              int* __restrict__ csr, int E) {
    int e = blockIdx.x * 256 + threadIdx.x;
    if (e < E) {
        int d = dst[e];
        int p = atomicAdd(&cursor[d], 1);
        csr[rowstart[d] + p] = src[e];
    }
}

// ---------- z[i] = h[i] + sum_{j in adj(i)} h[j] ----------
__global__ __launch_bounds__(256) void k_gather(const float* __restrict__ h, const int* __restrict__ rowstart,
                                                const int* __restrict__ deg, const int* __restrict__ csr,
                                                float* __restrict__ z, int N) {
    int gid = blockIdx.x * 256 + threadIdx.x;
    int node = gid >> 5, lane = gid & 31;
    if (node >= N) return;
    const float4* h4 = (const float4*)h;
    float4 acc = h4[(size_t)node * D4 + lane];
    int s = rowstart[node], n = deg[node];
    for (int k = 0; k < n; ++k) {
        int j = csr[s + k];
        float4 v = h4[(size_t)j * D4 + lane];
        acc.x += v.x; acc.y += v.y; acc.z += v.z; acc.w += v.w;
    }
    ((float4*)z)[(size_t)node * D4 + lane] = acc;
}

// ---------- fp32 GEMM: out[N,128] = in[N,128] @ W[128,128] + bias, optional ReLU ----------
#define FMA4(A, S, WV) do { (A).x = fmaf((S), (WV).x, (A).x); (A).y = fmaf((S), (WV).y, (A).y); \
                            (A).z = fmaf((S), (WV).z, (A).z); (A).w = fmaf((S), (WV).w, (A).w); } while (0)

template <bool RELU>
__global__ __launch_bounds__(256) void gemm128(const float* in, const float* __restrict__ W,
                                               const float* __restrict__ bias, float* out, int N) {
    __shared__ float4 wl4[4096];   // 64 KB: W[128][128]
    const float4* W4 = (const float4*)W;
    #pragma unroll
    for (int i = 0; i < 16; ++i) wl4[threadIdx.x + i * 256] = W4[threadIdx.x + i * 256];
    __syncthreads();

    const int cg = threadIdx.x & 31;   // 4 cols: 4*cg..4*cg+3
    const int rg = threadIdx.x >> 5;   // 8 row groups
    const int row0 = blockIdx.x * 64 + rg * 8;
    const float4* in4 = (const float4*)in;

    float4 bv = ((const float4*)bias)[cg];
    float4 acc[8];
    int rr[8];
    #pragma unroll
    for (int r = 0; r < 8; ++r) {
        acc[r] = bv;
        int q = row0 + r;
        rr[r] = (q < N) ? q : (N - 1);
    }

    for (int k4 = 0; k4 < 32; ++k4) {
        float4 wk0 = wl4[(k4 * 4 + 0) * 32 + cg];
        float4 wk1 = wl4[(k4 * 4 + 1) * 32 + cg];
        float4 wk2 = wl4[(k4 * 4 + 2) * 32 + cg];
        float4 wk3 = wl4[(k4 * 4 + 3) * 32 + cg];
        #pragma unroll
        for (int r = 0; r < 8; ++r) {
            float4 zv = in4[(size_t)rr[r] * D4 + k4];
            FMA4(acc[r], zv.x, wk0);
            FMA4(acc[r], zv.y, wk1);
            FMA4(acc[r], zv.z, wk2);
            FMA4(acc[r], zv.w, wk3);
        }
    }

    #pragma unroll
    for (int r = 0; r < 8; ++r) {
        int q = row0 + r;
        if (q < N) {
            float4 a = acc[r];
            if (RELU) {
                a.x = fmaxf(a.x, 0.f); a.y = fmaxf(a.y, 0.f);
                a.z = fmaxf(a.z, 0.f); a.w = fmaxf(a.w, 0.f);
            }
            ((float4*)out)[(size_t)q * D4 + cg] = a;
        }
    }
}

// ---------- column stats: stats[0..127]=sum, stats[128..255]=sumsq ----------
__global__ __launch_bounds__(256) void k_stats(const float* __restrict__ t, float* __restrict__ stats, int N) {
    int cg = threadIdx.x & 31, rg = threadIdx.x >> 5;
    float4 s = {0, 0, 0, 0}, q = {0, 0, 0, 0};
    for (int r = blockIdx.x * 8 + rg; r < N; r += gridDim.x * 8) {
        float4 v = ((const float4*)t)[(size_t)r * D4 + cg];
        s.x += v.x; s.y += v.y; s.z += v.z; s.w += v.w;
        q.x += v.x * v.x; q.y += v.y * v.y; q.z += v.z * v.z; q.w += v.w * v.w;
    }
    __shared__ float4 ls[256], lq[256];
    ls[threadIdx.x] = s; lq[threadIdx.x] = q;
    __syncthreads();
    if (rg == 0) {
        #pragma unroll
        for (int i = 1; i < 8; ++i) {
            float4 a = ls[i * 32 + cg]; s.x += a.x; s.y += a.y; s.z += a.z; s.w += a.w;
            float4 b = lq[i * 32 + cg]; q.x += b.x; q.y += b.y; q.z += b.z; q.w += b.w;
        }
        atomicAdd(&stats[cg * 4 + 0], s.x); atomicAdd(&stats[cg * 4 + 1], s.y);
        atomicAdd(&stats[cg * 4 + 2], s.z); atomicAdd(&stats[cg * 4 + 3], s.w);
        atomicAdd(&stats[128 + cg * 4 + 0], q.x); atomicAdd(&stats[128 + cg * 4 + 1], q.y);
        atomicAdd(&stats[128 + cg * 4 + 2], q.z); atomicAdd(&stats[128 + cg * 4 + 3], q.w);
    }
}

// ---------- per-column scale/shift from stats ----------
__global__ void k_finalize(const float* __restrict__ stats, const float* __restrict__ gw,
                           const float* __restrict__ gb, const float* __restrict__ ga,
                           float* __restrict__ scsh, int N) {
    int c = threadIdx.x;   // 128 threads
    float invN = 1.0f / (float)N;
    float m = stats[c] * invN;
    float msq = stats[128 + c] * invN;
    float a = ga[c];
    float var = msq - 2.f * a * m * m + a * a * m * m;   // E[(t-am)^2]
    float sc = gw[c] * rsqrtf(var + 1e-5f);
    scsh[c] = sc;
    scsh[128 + c] = gb[c] - sc * a * m;
}

// ---------- t = relu(scale*t + shift), in place ----------
__global__ __launch_bounds__(256) void k_normrelu(float* t, const float* __restrict__ scsh, int total4) {
    int gid = blockIdx.x * 256 + threadIdx.x;
    if (gid >= total4) return;
    int c4 = gid & 31;
    float4 sc = ((const float4*)scsh)[c4];
    float4 sh = ((const float4*)(scsh + 128))[c4];
    float4 v = ((float4*)t)[gid];
    v.x = fmaxf(fmaf(sc.x, v.x, sh.x), 0.f);
    v.y = fmaxf(fmaf(sc.y, v.y, sh.y), 0.f);
    v.z = fmaxf(fmaf(sc.z, v.z, sh.z), 0.f);
    v.w = fmaxf(fmaf(sc.w, v.w, sh.w), 0.f);
    ((float4*)t)[gid] = v;
}

extern "C" void kernel_launch(void* const* d_in, const int* in_sizes, int n_in,
                              void* d_out, int out_size, void* d_ws, size_t ws_size,
                              hipStream_t stream) {
    const float* x  = (const float*)d_in[0];
    const int*   ei = (const int*)d_in[1];
    const float* W1 = (const float*)d_in[2];
    const float* b1 = (const float*)d_in[3];
    const float* gw = (const float*)d_in[4];
    const float* gb = (const float*)d_in[5];
    const float* ga = (const float*)d_in[6];
    const float* W2 = (const float*)d_in[7];
    const float* b2 = (const float*)d_in[8];

    const int N = in_sizes[0] / D;
    const int E = in_sizes[1] / 2;
    const int L = in_sizes[2] / (D * D);
    const int* src  = ei;
    const int* dstp = ei + E;

    char* w = (char*)d_ws;
    size_t off = 0;
    float* bufB     = (float*)(w + off); off += (size_t)N * D * 4;
    int*   deg      = (int*)(w + off);   off += (size_t)N * 4;
    int*   cursor   = (int*)(w + off);   off += (size_t)N * 4;
    int*   rowstart = (int*)(w + off);   off += (size_t)N * 4;
    int*   csr      = (int*)(w + off);   off += (size_t)E * 4;
    int*   bsum     = (int*)(w + off);   off += 4096 * 4;
    int*   bofs     = (int*)(w + off);   off += 4096 * 4;
    float* stats    = (float*)(w + off); off += 256 * 4;
    float* scsh     = (float*)(w + off); off += 256 * 4;

    const int nsb = (N + 1023) / 1024;

    hipMemsetAsync(deg, 0, (size_t)N * 4, stream);
    hipMemsetAsync(cursor, 0, (size_t)N * 4, stream);
    k_hist<<<(E + 255) / 256, 256, 0, stream>>>(dstp, deg, E);
    k_scan1<<<nsb, 1024, 0, stream>>>(deg, rowstart, bsum, N);
    k_scan2<<<1, 1024, 0, stream>>>(bsum, bofs, nsb);
    k_scan3<<<nsb, 1024, 0, stream>>>(rowstart, bofs, N);
    k_fill<<<(E + 255) / 256, 256, 0, stream>>>(src, dstp, rowstart, cursor, csr, E);

    float* bufA = (float*)d_out;
    const float* h = x;
    const int gatherGrid = ((size_t)N * 32 + 255) / 256;
    const int gemmGrid = (N + 63) / 64;

    for (int l = 0; l < L; ++l) {
        float* zt = (l & 1) ? bufB : bufA;
        k_gather<<<gatherGrid, 256, 0, stream>>>(h, rowstart, deg, csr, zt, N);
        gemm128<false><<<gemmGrid, 256, 0, stream>>>(zt, W1 + (size_t)l * D * D, b1 + (size_t)l * D, zt, N);
        hipMemsetAsync(stats, 0, 256 * 4, stream);
        k_stats<<<512, 256, 0, stream>>>(zt, stats, N);
        k_finalize<<<1, 128, 0, stream>>>(stats, gw + (size_t)l * D, gb + (size_t)l * D, ga + (size_t)l * D, scsh, N);
        k_normrelu<<<gatherGrid, 256, 0, stream>>>(zt, scsh, (int)((size_t)N * D4));
        gemm128<true><<<gemmGrid, 256, 0, stream>>>(zt, W2 + (size_t)l * D * D, b2 + (size_t)l * D, zt, N);
        h = zt;
    }
}

// Round 2
// 569.661 us; speedup vs baseline: 2.4626x; 2.4626x over previous
//
#include <hip/hip_runtime.h>

#define D 128

typedef _Float16 f16;
typedef f16 f16x8 __attribute__((ext_vector_type(8)));
typedef float f32x4 __attribute__((ext_vector_type(4)));

// ---------- CSR build ----------
__global__ __launch_bounds__(256) void k_hist(const int* __restrict__ dst, int* __restrict__ deg, int E) {
    int e = blockIdx.x * 256 + threadIdx.x;
    if (e < E) atomicAdd(&deg[dst[e]], 1);
}

__global__ __launch_bounds__(1024) void k_scan1(const int* __restrict__ deg, int* __restrict__ rowstart,
                                                int* __restrict__ bsum, int N) {
    __shared__ int sd[1024];
    int i = blockIdx.x * 1024 + threadIdx.x;
    int v = (i < N) ? deg[i] : 0;
    sd[threadIdx.x] = v; __syncthreads();
    for (int off = 1; off < 1024; off <<= 1) {
        int t = (threadIdx.x >= off) ? sd[threadIdx.x - off] : 0;
        __syncthreads();
        sd[threadIdx.x] += t;
        __syncthreads();
    }
    if (i < N) rowstart[i] = sd[threadIdx.x] - v;   // exclusive
    if (threadIdx.x == 1023) bsum[blockIdx.x] = sd[1023];
}

__global__ __launch_bounds__(1024) void k_scan2(const int* __restrict__ bsum, int* __restrict__ bofs, int M) {
    __shared__ int sd[1024];
    int v = (threadIdx.x < M) ? bsum[threadIdx.x] : 0;
    sd[threadIdx.x] = v; __syncthreads();
    for (int off = 1; off < 1024; off <<= 1) {
        int t = (threadIdx.x >= off) ? sd[threadIdx.x - off] : 0;
        __syncthreads();
        sd[threadIdx.x] += t;
        __syncthreads();
    }
    if (threadIdx.x < M) bofs[threadIdx.x] = sd[threadIdx.x] - v;  // exclusive
}

__global__ __launch_bounds__(1024) void k_scan3(int* rowstart, const int* __restrict__ bofs, int N) {
    int i = blockIdx.x * 1024 + threadIdx.x;
    if (i < N) rowstart[i] += bofs[blockIdx.x];
}

__global__ __launch_bounds__(256) void k_fill(const int* __restrict__ src, const int* __restrict__ dst,
                                              const int* __restrict__ rowstart, int* __restrict__ cursor,
                                              int* __restrict__ csr, int E) {
    int e = blockIdx.x * 256 + threadIdx.x;
    if (e < E) {
        int d = dst[e];
        int p = atomicAdd(&cursor[d], 1);
        csr[rowstart[d] + p] = src[e];
    }
}

// ---------- x fp32 -> h f16 ----------
__global__ __launch_bounds__(256) void k_cvt(const float* __restrict__ x, f16* __restrict__ o, int n8) {
    int i = blockIdx.x * 256 + threadIdx.x;
    if (i >= n8) return;
    float4 a = ((const float4*)x)[2 * i];
    float4 b = ((const float4*)x)[2 * i + 1];
    f16x8 v;
    v[0] = (f16)a.x; v[1] = (f16)a.y; v[2] = (f16)a.z; v[3] = (f16)a.w;
    v[4] = (f16)b.x; v[5] = (f16)b.y; v[6] = (f16)b.z; v[7] = (f16)b.w;
    ((f16x8*)o)[i] = v;
}

// ---------- W fp32 [k][c] -> pre-swizzled f16 W^T image (LDS-linear) ----------
// wpre flat elem (m, c*128 + t*8 + j) = (f16) W_m[ ((t ^ (c&15))*8 + j) * 128 + c ]
__global__ __launch_bounds__(256) void k_prepw(const float* __restrict__ W1, const float* __restrict__ W2,
                                               f16* __restrict__ wpre, int L) {
    int idx = blockIdx.x * 256 + threadIdx.x;
    if (idx >= 2 * L * 16384) return;
    int m = idx >> 14, local = idx & 16383;
    int c = local >> 7, r = local & 127;
    int t = r >> 3, j = r & 7;
    int k = ((t ^ (c & 15)) << 3) | j;
    const float* Wsrc = (m < L) ? (W1 + (size_t)m * 16384) : (W2 + (size_t)(m - L) * 16384);
    wpre[idx] = (f16)Wsrc[k * 128 + c];
}

// ---------- z[i] = h[i] + sum_{j in adj(i)} h[j]  (f16 io, fp32 accum) ----------
__global__ __launch_bounds__(256) void k_gather16(const f16* __restrict__ h, const int* __restrict__ rowstart,
                                                  const int* __restrict__ deg, const int* __restrict__ csr,
                                                  f16* __restrict__ z, int N) {
    int gid = blockIdx.x * 256 + threadIdx.x;
    int node = gid >> 4, ln = gid & 15;
    if (node >= N) return;
    const int ro = ln * 8;
    f16x8 hv = *(const f16x8*)(h + (size_t)node * D + ro);
    float acc[8];
    #pragma unroll
    for (int j = 0; j < 8; ++j) acc[j] = (float)hv[j];
    const int s = rowstart[node], n = deg[node];
    for (int k = 0; k < n; ++k) {
        const int nb = csr[s + k];
        f16x8 v = *(const f16x8*)(h + (size_t)nb * D + ro);
        #pragma unroll
        for (int j = 0; j < 8; ++j) acc[j] += (float)v[j];
    }
    f16x8 o;
    #pragma unroll
    for (int j = 0; j < 8; ++j) o[j] = (f16)acc[j];
    *(f16x8*)(z + (size_t)node * D + ro) = o;
}

// ---------- MFMA GEMM: out[N,128] = f(in)[N,128] @ W[128,128] + bias ----------
// MIN_: 0 = raw f16 A;  1 = A := relu(sc*A + sh) per k-column (fused GraphNorm+ReLU)
// MOUT_: 0 = f16 store raw + fused column stats;  1 = f16 relu store;  2 = f32 relu store
template<int MIN_, int MOUT_>
__global__ __launch_bounds__(256, 2) void mfma_gemm(
    const f16* __restrict__ Ain, const f16* __restrict__ Wp,
    const float* __restrict__ bias, const float* __restrict__ scsh,
    void* __restrict__ outp, float* __restrict__ stats, int N)
{
    __shared__ f16 wlds[16384];   // W^T [c][k] f16, XOR-swizzled 16B slots
    __shared__ float sred[256];
    const int tid = threadIdx.x;
    #pragma unroll
    for (int p = 0; p < 8; ++p)
        ((float4*)wlds)[p * 256 + tid] = ((const float4*)Wp)[p * 256 + tid];
    if (MOUT_ == 0) sred[tid] = 0.f;
    __syncthreads();

    const int wid = tid >> 6, lane = tid & 63;
    const int l15 = lane & 15, l4 = lane >> 4;
    const int rowbase = blockIdx.x * 256 + wid * 64;

    f32x4 acc[4][8];
    #pragma unroll
    for (int rt = 0; rt < 4; ++rt)
        #pragma unroll
        for (int ct = 0; ct < 8; ++ct)
            acc[rt][ct] = (f32x4){0.f, 0.f, 0.f, 0.f};

    size_t arow[4];
    #pragma unroll
    for (int rt = 0; rt < 4; ++rt) {
        int r = rowbase + rt * 16 + l15;
        arow[rt] = (size_t)((r < N) ? r : (N - 1)) * D;
    }

    #pragma unroll
    for (int ks = 0; ks < 4; ++ks) {
        const int k0 = ks * 32 + l4 * 8;
        float scv[8], shv[8];
        if (MIN_) {
            *(float4*)(scv)     = *(const float4*)(scsh + k0);
            *(float4*)(scv + 4) = *(const float4*)(scsh + k0 + 4);
            *(float4*)(shv)     = *(const float4*)(scsh + 128 + k0);
            *(float4*)(shv + 4) = *(const float4*)(scsh + 128 + k0 + 4);
        }
        f16x8 a[4];
        #pragma unroll
        for (int rt = 0; rt < 4; ++rt) {
            a[rt] = *(const f16x8*)(Ain + arow[rt] + k0);
            if (MIN_) {
                #pragma unroll
                for (int j = 0; j < 8; ++j) {
                    float v = fmaf((float)a[rt][j], scv[j], shv[j]);
                    a[rt][j] = (f16)fmaxf(v, 0.f);
                }
            }
        }
        #pragma unroll
        for (int ct = 0; ct < 8; ++ct) {
            const int c = ct * 16 + l15;
            const int sl = (ks * 4 + l4) ^ (c & 15);
            f16x8 b = *(const f16x8*)(wlds + c * D + sl * 8);
            #pragma unroll
            for (int rt = 0; rt < 4; ++rt)
                acc[rt][ct] = __builtin_amdgcn_mfma_f32_16x16x32_f16(a[rt], b, acc[rt][ct], 0, 0, 0);
        }
    }

    f16* out16 = (f16*)outp;
    float* out32 = (float*)outp;
    #pragma unroll
    for (int ct = 0; ct < 8; ++ct) {
        const int col = ct * 16 + l15;
        const float bv = bias[col];
        float s = 0.f, q = 0.f;
        #pragma unroll
        for (int rt = 0; rt < 4; ++rt) {
            const int r0 = rowbase + rt * 16 + l4 * 4;
            #pragma unroll
            for (int rg = 0; rg < 4; ++rg) {
                const int row = r0 + rg;
                const float v = acc[rt][ct][rg] + bv;
                if (row < N) {
                    if (MOUT_ == 0)      { out16[(size_t)row * D + col] = (f16)v; s += v; q += v * v; }
                    else if (MOUT_ == 1) { out16[(size_t)row * D + col] = (f16)fmaxf(v, 0.f); }
                    else                 { out32[(size_t)row * D + col] = fmaxf(v, 0.f); }
                }
            }
        }
        if (MOUT_ == 0) { atomicAdd(&sred[col], s); atomicAdd(&sred[128 + col], q); }
    }
    if (MOUT_ == 0) { __syncthreads(); atomicAdd(&stats[tid], sred[tid]); }
}

// ---------- per-column scale/shift from stats ----------
__global__ void k_finalize(const float* __restrict__ stats, const float* __restrict__ gw,
                           const float* __restrict__ gb, const float* __restrict__ ga,
                           float* __restrict__ scsh, int N) {
    int c = threadIdx.x;   // 128 threads
    float invN = 1.0f / (float)N;
    float m = stats[c] * invN;
    float msq = stats[128 + c] * invN;
    float a = ga[c];
    float var = msq - 2.f * a * m * m + a * a * m * m;   // E[(t-am)^2]
    float sc = gw[c] * rsqrtf(var + 1e-5f);
    scsh[c] = sc;
    scsh[128 + c] = gb[c] - sc * a * m;
}

extern "C" void kernel_launch(void* const* d_in, const int* in_sizes, int n_in,
                              void* d_out, int out_size, void* d_ws, size_t ws_size,
                              hipStream_t stream) {
    const float* x  = (const float*)d_in[0];
    const int*   ei = (const int*)d_in[1];
    const float* W1 = (const float*)d_in[2];
    const float* b1 = (const float*)d_in[3];
    const float* gw = (const float*)d_in[4];
    const float* gb = (const float*)d_in[5];
    const float* ga = (const float*)d_in[6];
    const float* W2 = (const float*)d_in[7];
    const float* b2 = (const float*)d_in[8];

    const int N = in_sizes[0] / D;
    const int E = in_sizes[1] / 2;
    const int L = in_sizes[2] / (D * D);
    const int* src  = ei;
    const int* dstp = ei + E;

    char* w = (char*)d_ws;
    size_t off = 0;
    f16*   z        = (f16*)(w + off);   off += (size_t)N * D * 2;
    f16*   z2       = (f16*)(w + off);   off += (size_t)N * D * 2;
    f16*   wpre     = (f16*)(w + off);   off += (size_t)2 * L * 16384 * 2;
    int*   deg      = (int*)(w + off);   off += (size_t)N * 4;
    int*   cursor   = (int*)(w + off);   off += (size_t)N * 4;
    int*   rowstart = (int*)(w + off);   off += (size_t)N * 4;
    int*   csr      = (int*)(w + off);   off += (size_t)E * 4;
    int*   bsum     = (int*)(w + off);   off += 4096 * 4;
    int*   bofs     = (int*)(w + off);   off += 4096 * 4;
    float* stats    = (float*)(w + off); off += 256 * 4;
    float* scsh     = (float*)(w + off); off += 256 * 4;

    f16* h16 = (f16*)d_out;   // intermediate h lives in d_out's front (f16); final write is fp32 full

    const int nsb = (N + 1023) / 1024;
    hipMemsetAsync(deg, 0, (size_t)N * 4, stream);
    hipMemsetAsync(cursor, 0, (size_t)N * 4, stream);
    k_hist<<<(E + 255) / 256, 256, 0, stream>>>(dstp, deg, E);
    k_scan1<<<nsb, 1024, 0, stream>>>(deg, rowstart, bsum, N);
    k_scan2<<<1, 1024, 0, stream>>>(bsum, bofs, nsb);
    k_scan3<<<nsb, 1024, 0, stream>>>(rowstart, bofs, N);
    k_fill<<<(E + 255) / 256, 256, 0, stream>>>(src, dstp, rowstart, cursor, csr, E);

    k_cvt<<<((N * D / 8) + 255) / 256, 256, 0, stream>>>(x, h16, N * D / 8);
    k_prepw<<<((2 * L * 16384) + 255) / 256, 256, 0, stream>>>(W1, W2, wpre, L);

    const int gatherGrid = ((size_t)N * 16 + 255) / 256;
    const int gemmGrid = (N + 255) / 256;

    for (int l = 0; l < L; ++l) {
        k_gather16<<<gatherGrid, 256, 0, stream>>>(h16, rowstart, deg, csr, z, N);
        hipMemsetAsync(stats, 0, 256 * 4, stream);
        mfma_gemm<0, 0><<<gemmGrid, 256, 0, stream>>>(z, wpre + (size_t)l * 16384,
                                                      b1 + (size_t)l * D, scsh, z2, stats, N);
        k_finalize<<<1, 128, 0, stream>>>(stats, gw + (size_t)l * D, gb + (size_t)l * D,
                                          ga + (size_t)l * D, scsh, N);
        if (l < L - 1)
            mfma_gemm<1, 1><<<gemmGrid, 256, 0, stream>>>(z2, wpre + (size_t)(L + l) * 16384,
                                                          b2 + (size_t)l * D, scsh, h16, nullptr, N);
        else
            mfma_gemm<1, 2><<<gemmGrid, 256, 0, stream>>>(z2, wpre + (size_t)(L + l) * 16384,
                                                          b2 + (size_t)l * D, scsh, d_out, nullptr, N);
    }
}

// Round 3
// 525.891 us; speedup vs baseline: 2.6675x; 1.0832x over previous
//
#include <hip/hip_runtime.h>

#define D 128

typedef _Float16 f16;
typedef f16 f16x8 __attribute__((ext_vector_type(8)));
typedef float f32x4 __attribute__((ext_vector_type(4)));

// ---------- CSR build ----------
__global__ __launch_bounds__(256) void k_hist(const int* __restrict__ dst, int* __restrict__ deg, int E) {
    int e = blockIdx.x * 256 + threadIdx.x;
    if (e < E) atomicAdd(&deg[dst[e]], 1);
}

__global__ __launch_bounds__(1024) void k_scan1(const int* __restrict__ deg, int* __restrict__ rowstart,
                                                int* __restrict__ bsum, int N) {
    __shared__ int sd[1024];
    int i = blockIdx.x * 1024 + threadIdx.x;
    int v = (i < N) ? deg[i] : 0;
    sd[threadIdx.x] = v; __syncthreads();
    for (int off = 1; off < 1024; off <<= 1) {
        int t = (threadIdx.x >= off) ? sd[threadIdx.x - off] : 0;
        __syncthreads();
        sd[threadIdx.x] += t;
        __syncthreads();
    }
    if (i < N) rowstart[i] = sd[threadIdx.x] - v;   // exclusive
    if (threadIdx.x == 1023) bsum[blockIdx.x] = sd[1023];
}

__global__ __launch_bounds__(1024) void k_scan2(const int* __restrict__ bsum, int* __restrict__ bofs, int M) {
    __shared__ int sd[1024];
    int v = (threadIdx.x < M) ? bsum[threadIdx.x] : 0;
    sd[threadIdx.x] = v; __syncthreads();
    for (int off = 1; off < 1024; off <<= 1) {
        int t = (threadIdx.x >= off) ? sd[threadIdx.x - off] : 0;
        __syncthreads();
        sd[threadIdx.x] += t;
        __syncthreads();
    }
    if (threadIdx.x < M) bofs[threadIdx.x] = sd[threadIdx.x] - v;  // exclusive
}

__global__ __launch_bounds__(1024) void k_scan3(int* rowstart, const int* __restrict__ bofs, int N) {
    int i = blockIdx.x * 1024 + threadIdx.x;
    if (i < N) rowstart[i] += bofs[blockIdx.x];
}

__global__ __launch_bounds__(256) void k_fill(const int* __restrict__ src, const int* __restrict__ dst,
                                              const int* __restrict__ rowstart, int* __restrict__ cursor,
                                              int* __restrict__ csr, int E) {
    int e = blockIdx.x * 256 + threadIdx.x;
    if (e < E) {
        int d = dst[e];
        int p = atomicAdd(&cursor[d], 1);
        csr[rowstart[d] + p] = src[e];
    }
}

// ---------- x fp32 -> h f16 ----------
__global__ __launch_bounds__(256) void k_cvt(const float* __restrict__ x, f16* __restrict__ o, int n8) {
    int i = blockIdx.x * 256 + threadIdx.x;
    if (i >= n8) return;
    float4 a = ((const float4*)x)[2 * i];
    float4 b = ((const float4*)x)[2 * i + 1];
    f16x8 v;
    v[0] = (f16)a.x; v[1] = (f16)a.y; v[2] = (f16)a.z; v[3] = (f16)a.w;
    v[4] = (f16)b.x; v[5] = (f16)b.y; v[6] = (f16)b.z; v[7] = (f16)b.w;
    ((f16x8*)o)[i] = v;
}

// ---------- W fp32 [k][c] -> pre-swizzled f16 W^T image (LDS-linear) ----------
// wpre flat elem (m, c*128 + t*8 + j) = (f16) W_m[ ((t ^ (c&15))*8 + j) * 128 + c ]
__global__ __launch_bounds__(256) void k_prepw(const float* __restrict__ W1, const float* __restrict__ W2,
                                               f16* __restrict__ wpre, int L) {
    int idx = blockIdx.x * 256 + threadIdx.x;
    if (idx >= 2 * L * 16384) return;
    int m = idx >> 14, local = idx & 16383;
    int c = local >> 7, r = local & 127;
    int t = r >> 3, j = r & 7;
    int k = ((t ^ (c & 15)) << 3) | j;
    const float* Wsrc = (m < L) ? (W1 + (size_t)m * 16384) : (W2 + (size_t)(m - L) * 16384);
    wpre[idx] = (f16)Wsrc[k * 128 + c];
}

// ---------- z[i] = h[i] + sum_{j in adj(i)} h[j]  (f16 io, fp32 accum) ----------
__global__ __launch_bounds__(256) void k_gather16(const f16* __restrict__ h, const int* __restrict__ rowstart,
                                                  const int* __restrict__ deg, const int* __restrict__ csr,
                                                  f16* __restrict__ z, int N) {
    int gid = blockIdx.x * 256 + threadIdx.x;
    int node = gid >> 4, ln = gid & 15;
    if (node >= N) return;
    const int ro = ln * 8;
    f16x8 hv = *(const f16x8*)(h + (size_t)node * D + ro);
    float acc[8];
    #pragma unroll
    for (int j = 0; j < 8; ++j) acc[j] = (float)hv[j];
    const int s = rowstart[node], n = deg[node];
    for (int k = 0; k < n; ++k) {
        const int nb = csr[s + k];
        f16x8 v = *(const f16x8*)(h + (size_t)nb * D + ro);
        #pragma unroll
        for (int j = 0; j < 8; ++j) acc[j] += (float)v[j];
    }
    f16x8 o;
    #pragma unroll
    for (int j = 0; j < 8; ++j) o[j] = (f16)acc[j];
    *(f16x8*)(z + (size_t)node * D + ro) = o;
}

// ---------- MFMA GEMM: out[N,128] = f(in)[N,128] @ W[128,128] + bias ----------
// MIN_: 0 = raw f16 A;  1 = A := relu(sc*A + sh), sc/sh computed in-block from stats (fused GraphNorm)
// MOUT_: 0 = f16 raw store + fused column stats out;  1 = f16 relu store;  2 = f32 relu store
// Block: 256 threads / 4 waves; 128 rows per block; each wave 32 rows x 128 cols.
template<int MIN_, int MOUT_>
__global__ __launch_bounds__(256, 4) void mfma_gemm(
    const f16* __restrict__ Ain, const f16* __restrict__ Wp,
    const float* __restrict__ bias, const float* __restrict__ stats,
    const float* __restrict__ gw, const float* __restrict__ gb, const float* __restrict__ ga,
    void* __restrict__ outp, float* __restrict__ statsOut, int N)
{
    __shared__ f16 wlds[16384];     // 32 KB: W^T swizzled; reused as transpose staging after MFMAs
    __shared__ float blds[128];     // bias
    __shared__ float sclds[256];    // MIN_: scale[128] | shift[128]
    __shared__ float sred[256];     // MOUT_==0: sum[128] | sumsq[128]

    const int tid = threadIdx.x;
    #pragma unroll
    for (int p = 0; p < 8; ++p)
        ((float4*)wlds)[p * 256 + tid] = ((const float4*)Wp)[p * 256 + tid];
    if (MOUT_ == 0) { sred[tid] = 0.f; }
    if (tid < 128) {
        blds[tid] = bias[tid];
        if (MIN_) {
            float invN = 1.0f / (float)N;
            float m = stats[tid] * invN;
            float msq = stats[128 + tid] * invN;
            float a = ga[tid];
            float var = msq - 2.f * a * m * m + a * a * m * m;
            float sc = gw[tid] * rsqrtf(var + 1e-5f);
            sclds[tid] = sc;
            sclds[128 + tid] = gb[tid] - sc * a * m;
        }
    }
    __syncthreads();

    const int lane = tid & 63, wid = tid >> 6;
    const int l15 = lane & 15, l4 = lane >> 4;
    const int rowbase = blockIdx.x * 128 + wid * 32;

    f32x4 acc[2][8];
    #pragma unroll
    for (int rt = 0; rt < 2; ++rt)
        #pragma unroll
        for (int ct = 0; ct < 8; ++ct)
            acc[rt][ct] = (f32x4){0.f, 0.f, 0.f, 0.f};

    size_t arow[2];
    #pragma unroll
    for (int rt = 0; rt < 2; ++rt) {
        int r = rowbase + rt * 16 + l15;
        arow[rt] = (size_t)((r < N) ? r : (N - 1)) * D;
    }

    #pragma unroll
    for (int ks = 0; ks < 4; ++ks) {
        const int k0 = ks * 32 + l4 * 8;
        f16x8 a[2];
        #pragma unroll
        for (int rt = 0; rt < 2; ++rt) a[rt] = *(const f16x8*)(Ain + arow[rt] + k0);
        if (MIN_) {
            float scv[8], shv[8];
            *(float4*)(scv)     = *(const float4*)(sclds + k0);
            *(float4*)(scv + 4) = *(const float4*)(sclds + k0 + 4);
            *(float4*)(shv)     = *(const float4*)(sclds + 128 + k0);
            *(float4*)(shv + 4) = *(const float4*)(sclds + 128 + k0 + 4);
            #pragma unroll
            for (int rt = 0; rt < 2; ++rt)
                #pragma unroll
                for (int j = 0; j < 8; ++j) {
                    float v = fmaf((float)a[rt][j], scv[j], shv[j]);
                    a[rt][j] = (f16)fmaxf(v, 0.f);
                }
        }
        #pragma unroll
        for (int ct = 0; ct < 8; ++ct) {
            const int c = ct * 16 + l15;
            const int sl = (ks * 4 + l4) ^ (c & 15);
            f16x8 b = *(const f16x8*)(wlds + c * D + sl * 8);
            #pragma unroll
            for (int rt = 0; rt < 2; ++rt)
                acc[rt][ct] = __builtin_amdgcn_mfma_f32_16x16x32_f16(a[rt], b, acc[rt][ct], 0, 0, 0);
        }
    }

    // fused column stats (pre-ReLU values), LDS reduce
    if (MOUT_ == 0) {
        #pragma unroll
        for (int ct = 0; ct < 8; ++ct) {
            const int col = ct * 16 + l15;
            const float bv = blds[col];
            float s = 0.f, q = 0.f;
            #pragma unroll
            for (int rt = 0; rt < 2; ++rt) {
                const int r0 = rowbase + rt * 16 + l4 * 4;
                #pragma unroll
                for (int rg = 0; rg < 4; ++rg) {
                    if (r0 + rg < N) {
                        float v = acc[rt][ct][rg] + bv;
                        s += v; q += v * v;
                    }
                }
            }
            atomicAdd(&sred[col], s);
            atomicAdd(&sred[128 + col], q);
        }
    }

    __syncthreads();   // all waves done with W reads (and sred adds) before reuse

    if (MOUT_ == 0) atomicAdd(&statsOut[tid], sred[tid]);

    if (MOUT_ < 2) {
        // LDS-transpose epilogue: per-wave padded tile [16][136] f16 in own 8KB region
        f16* out16 = (f16*)outp;
        f16* tb = wlds + wid * 4096;
        #pragma unroll
        for (int rt = 0; rt < 2; ++rt) {
            #pragma unroll
            for (int ct = 0; ct < 8; ++ct) {
                const int col = ct * 16 + l15;
                const float bv = blds[col];
                #pragma unroll
                for (int rg = 0; rg < 4; ++rg) {
                    const int lrow = l4 * 4 + rg;
                    float v = acc[rt][ct][rg] + bv;
                    if (MOUT_ == 1) v = fmaxf(v, 0.f);
                    tb[lrow * 136 + col] = (f16)v;
                }
            }
            __syncthreads();
            #pragma unroll
            for (int it = 0; it < 4; ++it) {
                const int lrow = it * 4 + l4;
                const int chunk = l15;
                const int grow = rowbase + rt * 16 + lrow;
                f16x8 vv = *(const f16x8*)(tb + lrow * 136 + chunk * 8);
                if (grow < N) *(f16x8*)(out16 + (size_t)grow * D + chunk * 8) = vv;
            }
            __syncthreads();
        }
    } else {
        // last layer: direct f32 relu stores
        float* out32 = (float*)outp;
        #pragma unroll
        for (int ct = 0; ct < 8; ++ct) {
            const int col = ct * 16 + l15;
            const float bv = blds[col];
            #pragma unroll
            for (int rt = 0; rt < 2; ++rt) {
                const int r0 = rowbase + rt * 16 + l4 * 4;
                #pragma unroll
                for (int rg = 0; rg < 4; ++rg) {
                    const int row = r0 + rg;
                    if (row < N) out32[(size_t)row * D + col] = fmaxf(acc[rt][ct][rg] + bv, 0.f);
                }
            }
        }
    }
}

extern "C" void kernel_launch(void* const* d_in, const int* in_sizes, int n_in,
                              void* d_out, int out_size, void* d_ws, size_t ws_size,
                              hipStream_t stream) {
    const float* x  = (const float*)d_in[0];
    const int*   ei = (const int*)d_in[1];
    const float* W1 = (const float*)d_in[2];
    const float* b1 = (const float*)d_in[3];
    const float* gw = (const float*)d_in[4];
    const float* gb = (const float*)d_in[5];
    const float* ga = (const float*)d_in[6];
    const float* W2 = (const float*)d_in[7];
    const float* b2 = (const float*)d_in[8];

    const int N = in_sizes[0] / D;
    const int E = in_sizes[1] / 2;
    const int L = in_sizes[2] / (D * D);
    const int* src  = ei;
    const int* dstp = ei + E;

    char* w = (char*)d_ws;
    size_t off = 0;
    f16*   z        = (f16*)(w + off);   off += (size_t)N * D * 2;
    f16*   z2       = (f16*)(w + off);   off += (size_t)N * D * 2;
    f16*   wpre     = (f16*)(w + off);   off += (size_t)2 * L * 16384 * 2;
    int*   deg      = (int*)(w + off);   off += (size_t)N * 4;
    int*   cursor   = (int*)(w + off);   off += (size_t)N * 4;
    int*   rowstart = (int*)(w + off);   off += (size_t)N * 4;
    int*   csr      = (int*)(w + off);   off += (size_t)E * 4;
    int*   bsum     = (int*)(w + off);   off += 4096 * 4;
    int*   bofs     = (int*)(w + off);   off += 4096 * 4;
    float* statsL   = (float*)(w + off); off += (size_t)L * 256 * 4;

    f16* h16 = (f16*)d_out;   // intermediate h (f16) lives in d_out; final layer overwrites with f32

    const int nsb = (N + 1023) / 1024;
    hipMemsetAsync(deg, 0, (size_t)N * 4, stream);
    hipMemsetAsync(cursor, 0, (size_t)N * 4, stream);
    hipMemsetAsync(statsL, 0, (size_t)L * 256 * 4, stream);
    k_hist<<<(E + 255) / 256, 256, 0, stream>>>(dstp, deg, E);
    k_scan1<<<nsb, 1024, 0, stream>>>(deg, rowstart, bsum, N);
    k_scan2<<<1, 1024, 0, stream>>>(bsum, bofs, nsb);
    k_scan3<<<nsb, 1024, 0, stream>>>(rowstart, bofs, N);
    k_fill<<<(E + 255) / 256, 256, 0, stream>>>(src, dstp, rowstart, cursor, csr, E);

    k_cvt<<<((N * D / 8) + 255) / 256, 256, 0, stream>>>(x, h16, N * D / 8);
    k_prepw<<<((2 * L * 16384) + 255) / 256, 256, 0, stream>>>(W1, W2, wpre, L);

    const int gatherGrid = ((size_t)N * 16 + 255) / 256;
    const int gemmGrid = (N + 127) / 128;

    for (int l = 0; l < L; ++l) {
        float* st = statsL + (size_t)l * 256;
        k_gather16<<<gatherGrid, 256, 0, stream>>>(h16, rowstart, deg, csr, z, N);
        mfma_gemm<0, 0><<<gemmGrid, 256, 0, stream>>>(
            z, wpre + (size_t)l * 16384, b1 + (size_t)l * D,
            nullptr, nullptr, nullptr, nullptr, z2, st, N);
        if (l < L - 1)
            mfma_gemm<1, 1><<<gemmGrid, 256, 0, stream>>>(
                z2, wpre + (size_t)(L + l) * 16384, b2 + (size_t)l * D,
                st, gw + (size_t)l * D, gb + (size_t)l * D, ga + (size_t)l * D,
                h16, nullptr, N);
        else
            mfma_gemm<1, 2><<<gemmGrid, 256, 0, stream>>>(
                z2, wpre + (size_t)(L + l) * 16384, b2 + (size_t)l * D,
                st, gw + (size_t)l * D, gb + (size_t)l * D, ga + (size_t)l * D,
                d_out, nullptr, N);
    }
}

// Round 4
// 446.845 us; speedup vs baseline: 3.1394x; 1.1769x over previous
//
#include <hip/hip_runtime.h>

#define D 128

typedef _Float16 f16;
typedef f16 f16x8 __attribute__((ext_vector_type(8)));
typedef float f32x4 __attribute__((ext_vector_type(4)));

// ---------- CSR build ----------
__global__ __launch_bounds__(256) void k_hist(const int* __restrict__ dst, int* __restrict__ deg, int E) {
    int e = blockIdx.x * 256 + threadIdx.x;
    if (e < E) atomicAdd(&deg[dst[e]], 1);
}

__global__ __launch_bounds__(1024) void k_scan1(const int* __restrict__ deg, int* __restrict__ rowstart,
                                                int* __restrict__ bsum, int N) {
    __shared__ int sd[1024];
    int i = blockIdx.x * 1024 + threadIdx.x;
    int v = (i < N) ? deg[i] : 0;
    sd[threadIdx.x] = v; __syncthreads();
    for (int off = 1; off < 1024; off <<= 1) {
        int t = (threadIdx.x >= off) ? sd[threadIdx.x - off] : 0;
        __syncthreads();
        sd[threadIdx.x] += t;
        __syncthreads();
    }
    if (i < N) rowstart[i] = sd[threadIdx.x] - v;   // exclusive
    if (threadIdx.x == 1023) bsum[blockIdx.x] = sd[1023];
}

__global__ __launch_bounds__(1024) void k_scan2(const int* __restrict__ bsum, int* __restrict__ bofs, int M) {
    __shared__ int sd[1024];
    int v = (threadIdx.x < M) ? bsum[threadIdx.x] : 0;
    sd[threadIdx.x] = v; __syncthreads();
    for (int off = 1; off < 1024; off <<= 1) {
        int t = (threadIdx.x >= off) ? sd[threadIdx.x - off] : 0;
        __syncthreads();
        sd[threadIdx.x] += t;
        __syncthreads();
    }
    if (threadIdx.x < M) bofs[threadIdx.x] = sd[threadIdx.x] - v;  // exclusive
}

__global__ __launch_bounds__(1024) void k_scan3(int* rowstart, const int* __restrict__ bofs, int N) {
    int i = blockIdx.x * 1024 + threadIdx.x;
    if (i < N) rowstart[i] += bofs[blockIdx.x];
}

__global__ __launch_bounds__(256) void k_fill(const int* __restrict__ src, const int* __restrict__ dst,
                                              const int* __restrict__ rowstart, int* __restrict__ cursor,
                                              int* __restrict__ csr, int E) {
    int e = blockIdx.x * 256 + threadIdx.x;
    if (e < E) {
        int d = dst[e];
        int p = atomicAdd(&cursor[d], 1);
        csr[rowstart[d] + p] = src[e];
    }
}

// ---------- x fp32 -> h f16 ----------
__global__ __launch_bounds__(256) void k_cvt(const float* __restrict__ x, f16* __restrict__ o, int n8) {
    int i = blockIdx.x * 256 + threadIdx.x;
    if (i >= n8) return;
    float4 a = ((const float4*)x)[2 * i];
    float4 b = ((const float4*)x)[2 * i + 1];
    f16x8 v;
    v[0] = (f16)a.x; v[1] = (f16)a.y; v[2] = (f16)a.z; v[3] = (f16)a.w;
    v[4] = (f16)b.x; v[5] = (f16)b.y; v[6] = (f16)b.z; v[7] = (f16)b.w;
    ((f16x8*)o)[i] = v;
}

// ---------- W fp32 [k][c] -> pre-swizzled f16 W^T image (LDS-linear) ----------
__global__ __launch_bounds__(256) void k_prepw(const float* __restrict__ W1, const float* __restrict__ W2,
                                               f16* __restrict__ wpre, int L) {
    int idx = blockIdx.x * 256 + threadIdx.x;
    if (idx >= 2 * L * 16384) return;
    int m = idx >> 14, local = idx & 16383;
    int c = local >> 7, r = local & 127;
    int t = r >> 3, j = r & 7;
    int k = ((t ^ (c & 15)) << 3) | j;
    const float* Wsrc = (m < L) ? (W1 + (size_t)m * 16384) : (W2 + (size_t)(m - L) * 16384);
    wpre[idx] = (f16)Wsrc[k * 128 + c];
}

// ---------- z[i] = h[i] + sum_{j in adj(i)} h[j]  (f16 io, fp32 accum) ----------
__global__ __launch_bounds__(256) void k_gather16(const f16* __restrict__ h, const int* __restrict__ rowstart,
                                                  const int* __restrict__ deg, const int* __restrict__ csr,
                                                  f16* __restrict__ z, int N) {
    int gid = blockIdx.x * 256 + threadIdx.x;
    int node = gid >> 4, ln = gid & 15;
    if (node >= N) return;
    const int ro = ln * 8;
    f16x8 hv = *(const f16x8*)(h + (size_t)node * D + ro);
    float acc[8];
    #pragma unroll
    for (int j = 0; j < 8; ++j) acc[j] = (float)hv[j];
    const int s = rowstart[node], n = deg[node];
    for (int k = 0; k < n; ++k) {
        const int nb = csr[s + k];
        f16x8 v = *(const f16x8*)(h + (size_t)nb * D + ro);
        #pragma unroll
        for (int j = 0; j < 8; ++j) acc[j] += (float)v[j];
    }
    f16x8 o;
    #pragma unroll
    for (int j = 0; j < 8; ++j) o[j] = (f16)acc[j];
    *(f16x8*)(z + (size_t)node * D + ro) = o;
}

// ---------- MFMA GEMM: out[N,128] = f(in)[N,128] @ W[128,128] + bias ----------
// MIN_: 0 = raw f16 A;  1 = A := relu(sc*A + sh), sc/sh from per-layer stats (fused GraphNorm)
// MOUT_: 0 = f16 raw store + per-block column stat partials;  1 = f16 relu store;  2 = f32 relu store
// Block: 256 threads / 4 waves; 64 rows/block; each wave 16 rows x 128 cols, acc[8]=32 regs.
template<int MIN_, int MOUT_>
__global__ __launch_bounds__(256, 4) void mfma_gemm(
    const f16* __restrict__ Ain, const f16* __restrict__ Wp,
    const float* __restrict__ bias, const float* __restrict__ stats,
    const float* __restrict__ gw, const float* __restrict__ gb, const float* __restrict__ ga,
    void* __restrict__ outp, float* __restrict__ partials, int N)
{
    __shared__ f16 wlds[16384];     // 32KB W^T swizzled; reused for stats partials + transpose staging
    __shared__ float blds[128];
    __shared__ float sclds[256];

    const int tid = threadIdx.x;
    #pragma unroll
    for (int p = 0; p < 8; ++p)
        ((float4*)wlds)[p * 256 + tid] = ((const float4*)Wp)[p * 256 + tid];
    if (tid < 128) {
        blds[tid] = bias[tid];
        if (MIN_) {
            float invN = 1.0f / (float)N;
            float m = stats[tid] * invN;
            float msq = stats[128 + tid] * invN;
            float a = ga[tid];
            float var = msq - 2.f * a * m * m + a * a * m * m;
            float sc = gw[tid] * rsqrtf(var + 1e-5f);
            sclds[tid] = sc;
            sclds[128 + tid] = gb[tid] - sc * a * m;
        }
    }
    __syncthreads();

    const int lane = tid & 63, wid = tid >> 6;
    const int l15 = lane & 15, l4 = lane >> 4;
    const int rowA = blockIdx.x * 64 + wid * 16 + l15;
    const size_t arow = (size_t)((rowA < N) ? rowA : (N - 1)) * D;

    // prefetch ALL A fragments (4 x 16B per thread) before the MFMA chain
    f16x8 a[4];
    #pragma unroll
    for (int ks = 0; ks < 4; ++ks)
        a[ks] = *(const f16x8*)(Ain + arow + ks * 32 + l4 * 8);

    if (MIN_) {
        #pragma unroll
        for (int ks = 0; ks < 4; ++ks) {
            const int k0 = ks * 32 + l4 * 8;
            float scv[8], shv[8];
            *(float4*)(scv)     = *(const float4*)(sclds + k0);
            *(float4*)(scv + 4) = *(const float4*)(sclds + k0 + 4);
            *(float4*)(shv)     = *(const float4*)(sclds + 128 + k0);
            *(float4*)(shv + 4) = *(const float4*)(sclds + 128 + k0 + 4);
            #pragma unroll
            for (int j = 0; j < 8; ++j) {
                float v = fmaf((float)a[ks][j], scv[j], shv[j]);
                a[ks][j] = (f16)fmaxf(v, 0.f);
            }
        }
    }

    f32x4 acc[8];
    #pragma unroll
    for (int ct = 0; ct < 8; ++ct) acc[ct] = (f32x4){0.f, 0.f, 0.f, 0.f};

    #pragma unroll
    for (int ks = 0; ks < 4; ++ks) {
        #pragma unroll
        for (int ct = 0; ct < 8; ++ct) {
            const int c = ct * 16 + l15;
            const int sl = (ks * 4 + l4) ^ (c & 15);
            f16x8 b = *(const f16x8*)(wlds + c * D + sl * 8);
            acc[ct] = __builtin_amdgcn_mfma_f32_16x16x32_f16(a[ks], b, acc[ct], 0, 0, 0);
        }
    }

    __syncthreads();   // all W reads done; wlds reusable

    if (MOUT_ == 0) {
        // column stats: intra-wave shfl reduce -> LDS [4][512] -> cross-wave -> per-block partials
        float* sp = (float*)wlds;
        const int r0 = blockIdx.x * 64 + wid * 16 + l4 * 4;
        #pragma unroll
        for (int ct = 0; ct < 8; ++ct) {
            const int col = ct * 16 + l15;
            const float bv = blds[col];
            float s = 0.f, q = 0.f;
            #pragma unroll
            for (int rg = 0; rg < 4; ++rg) {
                if (r0 + rg < N) {
                    float v = acc[ct][rg] + bv;
                    s += v; q += v * v;
                }
            }
            s += __shfl_xor(s, 16); s += __shfl_xor(s, 32);
            q += __shfl_xor(q, 16); q += __shfl_xor(q, 32);
            if (l4 == 0) { sp[wid * 512 + col] = s; sp[wid * 512 + 128 + col] = q; }
        }
        __syncthreads();
        float v = sp[tid] + sp[512 + tid] + sp[1024 + tid] + sp[1536 + tid];
        partials[(size_t)blockIdx.x * 256 + tid] = v;
        __syncthreads();   // stats reads done before transpose overwrites wlds
    }

    if (MOUT_ < 2) {
        // LDS-transpose epilogue: per-wave [16][136] f16 tile in private 8KB region
        f16* out16 = (f16*)outp;
        f16* tb = wlds + wid * 4096;
        #pragma unroll
        for (int ct = 0; ct < 8; ++ct) {
            const int col = ct * 16 + l15;
            const float bv = blds[col];
            #pragma unroll
            for (int rg = 0; rg < 4; ++rg) {
                float v = acc[ct][rg] + bv;
                if (MOUT_ == 1) v = fmaxf(v, 0.f);
                tb[(l4 * 4 + rg) * 136 + col] = (f16)v;
            }
        }
        // per-wave private region: compiler inserts lgkmcnt waits; no barrier needed
        #pragma unroll
        for (int it = 0; it < 4; ++it) {
            const int lrow = it * 4 + l4;
            const int grow = blockIdx.x * 64 + wid * 16 + lrow;
            f16x8 vv = *(const f16x8*)(tb + lrow * 136 + l15 * 8);
            if (grow < N) *(f16x8*)(out16 + (size_t)grow * D + l15 * 8) = vv;
        }
    } else {
        float* out32 = (float*)outp;
        const int r0 = blockIdx.x * 64 + wid * 16 + l4 * 4;
        #pragma unroll
        for (int ct = 0; ct < 8; ++ct) {
            const int col = ct * 16 + l15;
            const float bv = blds[col];
            #pragma unroll
            for (int rg = 0; rg < 4; ++rg) {
                const int row = r0 + rg;
                if (row < N) out32[(size_t)row * D + col] = fmaxf(acc[ct][rg] + bv, 0.f);
            }
        }
    }
}

// ---------- reduce per-block stat partials -> stats[256] ----------
__global__ __launch_bounds__(256) void k_redstats(const float* __restrict__ partials,
                                                  float* __restrict__ stats, int nblk) {
    float acc = 0.f;
    for (int b = blockIdx.x; b < nblk; b += gridDim.x)
        acc += partials[(size_t)b * 256 + threadIdx.x];
    atomicAdd(&stats[threadIdx.x], acc);
}

extern "C" void kernel_launch(void* const* d_in, const int* in_sizes, int n_in,
                              void* d_out, int out_size, void* d_ws, size_t ws_size,
                              hipStream_t stream) {
    const float* x  = (const float*)d_in[0];
    const int*   ei = (const int*)d_in[1];
    const float* W1 = (const float*)d_in[2];
    const float* b1 = (const float*)d_in[3];
    const float* gw = (const float*)d_in[4];
    const float* gb = (const float*)d_in[5];
    const float* ga = (const float*)d_in[6];
    const float* W2 = (const float*)d_in[7];
    const float* b2 = (const float*)d_in[8];

    const int N = in_sizes[0] / D;
    const int E = in_sizes[1] / 2;
    const int L = in_sizes[2] / (D * D);
    const int* src  = ei;
    const int* dstp = ei + E;

    const int gemmGrid = (N + 63) / 64;

    char* w = (char*)d_ws;
    size_t off = 0;
    f16*   z        = (f16*)(w + off);   off += (size_t)N * D * 2;
    f16*   z2       = (f16*)(w + off);   off += (size_t)N * D * 2;
    f16*   wpre     = (f16*)(w + off);   off += (size_t)2 * L * 16384 * 2;
    int*   deg      = (int*)(w + off);   off += (size_t)N * 4;
    int*   cursor   = (int*)(w + off);   off += (size_t)N * 4;
    int*   rowstart = (int*)(w + off);   off += (size_t)N * 4;
    int*   csr      = (int*)(w + off);   off += (size_t)E * 4;
    int*   bsum     = (int*)(w + off);   off += 4096 * 4;
    int*   bofs     = (int*)(w + off);   off += 4096 * 4;
    float* statsL   = (float*)(w + off); off += (size_t)L * 256 * 4;
    float* partials = (float*)(w + off); off += (size_t)gemmGrid * 256 * 4;

    f16* h16 = (f16*)d_out;   // intermediate h (f16) in d_out front; final layer overwrites f32

    const int nsb = (N + 1023) / 1024;
    hipMemsetAsync(deg, 0, (size_t)N * 4, stream);
    hipMemsetAsync(cursor, 0, (size_t)N * 4, stream);
    hipMemsetAsync(statsL, 0, (size_t)L * 256 * 4, stream);
    k_hist<<<(E + 255) / 256, 256, 0, stream>>>(dstp, deg, E);
    k_scan1<<<nsb, 1024, 0, stream>>>(deg, rowstart, bsum, N);
    k_scan2<<<1, 1024, 0, stream>>>(bsum, bofs, nsb);
    k_scan3<<<nsb, 1024, 0, stream>>>(rowstart, bofs, N);
    k_fill<<<(E + 255) / 256, 256, 0, stream>>>(src, dstp, rowstart, cursor, csr, E);

    k_cvt<<<((N * D / 8) + 255) / 256, 256, 0, stream>>>(x, h16, N * D / 8);
    k_prepw<<<((2 * L * 16384) + 255) / 256, 256, 0, stream>>>(W1, W2, wpre, L);

    const int gatherGrid = ((size_t)N * 16 + 255) / 256;

    for (int l = 0; l < L; ++l) {
        float* st = statsL + (size_t)l * 256;
        k_gather16<<<gatherGrid, 256, 0, stream>>>(h16, rowstart, deg, csr, z, N);
        mfma_gemm<0, 0><<<gemmGrid, 256, 0, stream>>>(
            z, wpre + (size_t)l * 16384, b1 + (size_t)l * D,
            nullptr, nullptr, nullptr, nullptr, z2, partials, N);
        k_redstats<<<64, 256, 0, stream>>>(partials, st, gemmGrid);
        if (l < L - 1)
            mfma_gemm<1, 1><<<gemmGrid, 256, 0, stream>>>(
                z2, wpre + (size_t)(L + l) * 16384, b2 + (size_t)l * D,
                st, gw + (size_t)l * D, gb + (size_t)l * D, ga + (size_t)l * D,
                h16, nullptr, N);
        else
            mfma_gemm<1, 2><<<gemmGrid, 256, 0, stream>>>(
                z2, wpre + (size_t)(L + l) * 16384, b2 + (size_t)l * D,
                st, gw + (size_t)l * D, gb + (size_t)l * D, ga + (size_t)l * D,
                d_out, nullptr, N);
    }
}